// Round 12
// baseline (58.799 us; speedup 1.0000x reference)
//
#include <hip/hip_runtime.h>
#include <math.h>

namespace {

constexpr float kAlpha   = 0.75f;
constexpr int   kNumNeg  = 10000;
constexpr int   kNumHard = 100;
constexpr int   kRatio   = 100;
constexpr int   kB       = 8;
constexpr int   kN       = 64 * 128 * 128;   // 1048576
constexpr int   kTpb     = 256;
constexpr int   kWaves   = kTpb / 64;                      // 4
constexpr int   kGatherBlocks = (kB * kNumNeg + kTpb - 1) / kTpb;  // 313
constexpr int   kSlices  = 256;                            // stream blocks/batch
constexpr int   kStreamBlocks = kB * kSlices;              // 2048
constexpr int   kVPer    = (kNumNeg + kTpb - 1) / kTpb;    // 40
constexpr unsigned kSentinel = 0xFFFFFFFFu;

// workspace layout (word offsets)
constexpr int oPartials  = 0;       // 2048*2 floats
constexpr int oBatchLoss = 4096;    // 8 floats
constexpr int oCnt       = 4112;    // 8 u32 per-batch arrival counters
constexpr int oGCnt      = 4120;    // 1 u32 global counter
constexpr int oGvals     = 4352;    // 80000 u32

__device__ __forceinline__ float loss_at(float pred, float target, float mask) {
    float prob = 1.0f / (1.0f + expf(-pred));
    prob = fminf(fmaxf(prob, 1.0e-4f), 1.0f - 1.0e-4f);
    bool pos = (target == 1.0f);
    float alpha_f = pos ? kAlpha : (1.0f - kAlpha);
    float pt = pos ? (1.0f - prob) : prob;
    float focal_w = alpha_f * pt * pt;
    float bce = fmaxf(pred, 0.0f) - pred * target + log1pf(expf(-fabsf(pred)));
    float loss = (mask == 0.0f) ? focal_w * bce : 0.0f;
    if (pos && prob < 0.8f) loss *= 4.0f;
    return loss;
}

// Relaxed device-scope accessors (R11-proven: coherent-point traffic, no
// cache maintenance). Used ONLY for tiny partials/losses/counters.
__device__ __forceinline__ void cstoref(float* p, float v) {
    __hip_atomic_store(p, v, __ATOMIC_RELAXED, __HIP_MEMORY_SCOPE_AGENT);
}
__device__ __forceinline__ float cloadf(const float* p) {
    return __hip_atomic_load(p, __ATOMIC_RELAXED, __HIP_MEMORY_SCOPE_AGENT);
}

// K1: gather only. Normal coalesced stores to gvals (K1->K2 kernel boundary
// makes them visible to K2's cached loads). Block 0 resets the counters.
__global__ void __launch_bounds__(kTpb) gather_kernel(
        const float* __restrict__ pred, const float* __restrict__ target,
        const float* __restrict__ mask, const int* __restrict__ neg_idx,
        unsigned* __restrict__ ws) {
    if (blockIdx.x == 0 && threadIdx.x < 9) ws[oCnt + threadIdx.x] = 0u;
    const int t = blockIdx.x * kTpb + threadIdx.x;
    if (t >= kB * kNumNeg) return;
    const int b = t / kNumNeg;
    const int j = t - b * kNumNeg;
    const size_t base = (size_t)b * kN;
    const int gi = neg_idx[(size_t)b * kNumNeg + j];
    const float tg = target[base + gi];
    unsigned outv;
    if (tg == 1.0f) {
        outv = kSentinel;
    } else {
        float v = loss_at(pred[base + gi], tg, mask[base + gi]);
        outv = __float_as_uint(v);               // v >= 0, finite
    }
    ws[oGvals + (size_t)b * kNumNeg + j] = outv;
}

// K2: 2048 stream blocks (R10's exact stream shape). Per batch, the 256th
// arriver (relaxed fetch_add after vmcnt drain) runs the radix select
// inline with 256 threads — overlapped under the other batches' streams.
__global__ void __launch_bounds__(kTpb) stream_select_kernel(
        const float* __restrict__ pred, const float* __restrict__ target,
        const float* __restrict__ mask, unsigned* __restrict__ ws,
        float* __restrict__ out) {
    const int blk = blockIdx.x;
    const int tid = threadIdx.x;
    const int wave = tid >> 6, lane = tid & 63;
    float* wsf = (float*)ws;

    __shared__ unsigned whist[2][kWaves][256];   // 8 KB ping-pong
    __shared__ float r0[kWaves], r1[kWaves], r2[kWaves], r3[kWaves];
    __shared__ float red[kWaves];
    __shared__ float sh_np, sh_ps;
    __shared__ unsigned sh_krem, sh_prefix;
    __shared__ int sh_done, sh_last;

    // ---- stream role (identical math to R10) ----
    const int b = blk >> 8;
    const int slice = blk & 255;
    const size_t base = (size_t)b * kN;
    const float4* t4 = (const float4*)(target + base);
    const int tb = slice * kTpb + tid;           // [0, 65536)
    constexpr int kStride = kSlices * kTpb;      // 65536; nvec = 4*kStride
    float4 v0 = t4[tb];
    float4 v1 = t4[tb + kStride];
    float4 v2 = t4[tb + 2 * kStride];
    float4 v3 = t4[tb + 3 * kStride];

    float cnt = 0.0f, psum = 0.0f;
    const float4 vv[4] = {v0, v1, v2, v3};
    #pragma unroll
    for (int it = 0; it < 4; ++it) {
        const int i = tb + it * kStride;
        float tvv[4] = {vv[it].x, vv[it].y, vv[it].z, vv[it].w};
        #pragma unroll
        for (int c = 0; c < 4; ++c) {
            if (tvv[c] == 1.0f) {
                int gi = i * 4 + c;
                cnt += 1.0f;
                psum += loss_at(pred[base + gi], 1.0f, mask[base + gi]);
            }
        }
    }
    #pragma unroll
    for (int off = 32; off > 0; off >>= 1) {
        cnt  += __shfl_down(cnt, off);
        psum += __shfl_down(psum, off);
    }
    if (lane == 0) { r0[wave] = cnt; r1[wave] = psum; }
    __syncthreads();
    if (tid == 0) {
        float c = 0.0f, p = 0.0f;
        for (int w = 0; w < kWaves; ++w) { c += r0[w]; p += r1[w]; }
        float* slot = wsf + oPartials + ((size_t)b * kSlices + slice) * 2;
        cstoref(&slot[0], c);
        cstoref(&slot[1], p);
        asm volatile("s_waitcnt vmcnt(0)" ::: "memory");   // stores at L2
        unsigned old = __hip_atomic_fetch_add(&ws[oCnt + b], 1u,
                                              __ATOMIC_RELAXED,
                                              __HIP_MEMORY_SCOPE_AGENT);
        sh_last = (old == (unsigned)(kSlices - 1));
    }
    __syncthreads();
    if (!sh_last) return;

    // ================ finisher: radix select for batch b ================
    for (int i = tid; i < 2 * kWaves * 256; i += kTpb)
        ((unsigned*)whist)[i] = 0u;
    __syncthreads();

    // gvals: NORMAL cached loads (visible via K1->K2 kernel boundary)
    unsigned vreg[kVPer];
    float mcnt = 0.0f, msum = 0.0f;
    #pragma unroll
    for (int it = 0; it < kVPer; ++it) {
        const int j = tid + it * kTpb;
        unsigned v = kSentinel;
        if (j < kNumNeg) v = ws[oGvals + (size_t)b * kNumNeg + j];
        vreg[it] = v;
        if (v != kSentinel) {
            mcnt += 1.0f;
            msum += __uint_as_float(v);
            atomicAdd(&whist[0][wave][v >> 24], 1u);   // v>=0 → bucket <128
        }
    }
    float c = 0.0f, p = 0.0f;
    {   // partials: relaxed loads (one slot per thread)
        const float* slot = wsf + oPartials + ((size_t)b * kSlices + tid) * 2;
        c = cloadf(&slot[0]); p = cloadf(&slot[1]);
    }
    #pragma unroll
    for (int off = 32; off > 0; off >>= 1) {
        mcnt += __shfl_down(mcnt, off);
        msum += __shfl_down(msum, off);
        c    += __shfl_down(c, off);
        p    += __shfl_down(p, off);
    }
    if (lane == 0) { r0[wave] = mcnt; r1[wave] = msum; r2[wave] = c; r3[wave] = p; }
    __syncthreads();
    float my_loss = 0.0f;              // only thread 0's value used
    if (tid == 0) {
        float a0 = 0, a1 = 0, a2 = 0, a3 = 0;
        for (int w = 0; w < kWaves; ++w) { a0 += r0[w]; a1 += r1[w]; a2 += r2[w]; a3 += r3[w]; }
        sh_np = a2; sh_ps = a3;
        const int num_pos = (int)a2;
        const int m = (int)a0;
        const int k = (num_pos > 0) ? min(kRatio * num_pos, kNumNeg) : kNumHard;
        if (k >= m) {
            my_loss = (a3 + a1) / fmaxf(a2, 1.0f);
            sh_done = 1;
        } else {
            sh_done = 0;
            sh_krem = (unsigned)k;
            sh_prefix = 0u;
        }
    }
    __syncthreads();

    if (!sh_done) {
        #pragma unroll
        for (int pass = 0; pass < 4; ++pass) {
            const int shift = 24 - 8 * pass;
            if (pass > 0) {
                const unsigned pmask = 0xFFFFFFFFu << (shift + 8);
                const unsigned pval = sh_prefix;
                #pragma unroll
                for (int it = 0; it < kVPer; ++it) {
                    unsigned v = vreg[it];
                    if (v != kSentinel && (v & pmask) == pval)
                        atomicAdd(&whist[pass & 1][wave][(v >> shift) & 255u], 1u);
                }
                __syncthreads();
            }
            if (wave == 0) {
                const int binbase = 252 - 4 * lane;
                unsigned v0h = 0, v1h = 0, v2h = 0, v3h = 0;
                #pragma unroll
                for (int w = 0; w < kWaves; ++w) {
                    uint4 q = *(const uint4*)&whist[pass & 1][w][binbase];
                    v0h += q.x; v1h += q.y; v2h += q.z; v3h += q.w;
                }
                const unsigned d0 = v3h, d1 = v2h, d2 = v1h, d3 = v0h;
                const unsigned p0 = d0, p1 = p0 + d1, p2 = p1 + d2, p3 = p2 + d3;
                unsigned acc = p3;
                #pragma unroll
                for (int off = 1; off < 64; off <<= 1) {
                    unsigned y = __shfl_up(acc, off);
                    if (lane >= off) acc += y;
                }
                const unsigned excl = acc - p3;        // sfx of bin binbase+4
                const unsigned krem = sh_krem;
                const unsigned s0 = excl + p0, s1 = excl + p1,
                               s2 = excl + p2, s3 = excl + p3;
                if (s0 >= krem && excl < krem) {
                    sh_krem = krem - (s0 - d0);
                    sh_prefix |= (unsigned)(binbase + 3) << shift;
                } else if (s1 >= krem && s0 < krem) {
                    sh_krem = krem - (s1 - d1);
                    sh_prefix |= (unsigned)(binbase + 2) << shift;
                } else if (s2 >= krem && s1 < krem) {
                    sh_krem = krem - (s2 - d2);
                    sh_prefix |= (unsigned)(binbase + 1) << shift;
                } else if (s3 >= krem && s2 < krem) {
                    sh_krem = krem - (s3 - d3);
                    sh_prefix |= (unsigned)(binbase + 0) << shift;
                }
            } else {
                // waves 1-3: zero the OTHER buffer for the next pass
                for (int i = tid - 64; i < kWaves * 256; i += kTpb - 64)
                    ((unsigned*)whist[(pass + 1) & 1])[i] = 0u;
            }
            __syncthreads();
        }

        const unsigned tbits = sh_prefix;
        float gsum = 0.0f;
        #pragma unroll
        for (int it = 0; it < kVPer; ++it) {
            unsigned v = vreg[it];
            if (v != kSentinel && v > tbits) gsum += __uint_as_float(v);
        }
        #pragma unroll
        for (int off = 32; off > 0; off >>= 1) gsum += __shfl_down(gsum, off);
        if (lane == 0) red[wave] = gsum;
        __syncthreads();
        if (tid == 0) {
            float sum_gt = 0.0f;
            for (int w = 0; w < kWaves; ++w) sum_gt += red[w];
            const float tval = __uint_as_float(tbits);
            const float neg_sum = sum_gt + (float)sh_krem * tval;
            my_loss = (sh_ps + neg_sum) / fmaxf(sh_np, 1.0f);
        }
    }

    // ---- finalize: 8th batch-finisher computes the mean (fixed order) ----
    if (tid == 0) {
        cstoref(&wsf[oBatchLoss + b], my_loss);
        asm volatile("s_waitcnt vmcnt(0)" ::: "memory");
        unsigned old = __hip_atomic_fetch_add(&ws[oGCnt], 1u, __ATOMIC_RELAXED,
                                              __HIP_MEMORY_SCOPE_AGENT);
        if (old == (unsigned)(kB - 1)) {
            float s = 0.0f;
            for (int i = 0; i < kB; ++i)
                s += cloadf(&wsf[oBatchLoss + i]);
            out[0] = s / (float)kB;
        }
    }
}

} // namespace

extern "C" void kernel_launch(void* const* d_in, const int* in_sizes, int n_in,
                              void* d_out, int out_size, void* d_ws, size_t ws_size,
                              hipStream_t stream) {
    const float* pred   = (const float*)d_in[0];
    const float* target = (const float*)d_in[1];
    const float* mask   = (const float*)d_in[2];
    const int*   negidx = (const int*)d_in[3];
    unsigned* ws = (unsigned*)d_ws;
    float* out = (float*)d_out;

    gather_kernel<<<dim3(kGatherBlocks), dim3(kTpb), 0, stream>>>(
        pred, target, mask, negidx, ws);
    stream_select_kernel<<<dim3(kStreamBlocks), dim3(kTpb), 0, stream>>>(
        pred, target, mask, ws, out);
}

// Round 13
// 33.543 us; speedup vs baseline: 1.7529x; 1.7529x over previous
//
#include <hip/hip_runtime.h>
#include <math.h>

namespace {

constexpr float kAlpha   = 0.75f;
constexpr int   kNumNeg  = 10000;
constexpr int   kNumHard = 100;
constexpr int   kRatio   = 100;
constexpr int   kB       = 8;
constexpr int   kN       = 64 * 128 * 128;   // 1048576
constexpr int   kTpb1    = 256;              // K1 gather
constexpr int   kGatherBlocks = (kB * kNumNeg + kTpb1 - 1) / kTpb1;  // 313
constexpr int   kTpb2    = 1024;             // K2 stream+select
constexpr int   kWaves   = kTpb2 / 64;       // 16
constexpr int   kStreamPerB = 64;            // stream blocks per batch
constexpr int   kStreamBlocks = kB * kStreamPerB;   // 512
constexpr int   kVPer    = (kNumNeg + kTpb2 - 1) / kTpb2;  // 10
constexpr unsigned kSentinel = 0xFFFFFFFFu;

// workspace layout (word offsets)
constexpr int oPartials  = 0;       // 512*2 floats
constexpr int oBatchLoss = 1024;    // 8 floats
constexpr int oCnt       = 1040;    // 8 u32 per-batch arrival counters
constexpr int oGCnt      = 1048;    // 1 u32 global counter
constexpr int oGvals     = 1536;    // 80000 u32

__device__ __forceinline__ float loss_at(float pred, float target, float mask) {
    float prob = 1.0f / (1.0f + expf(-pred));
    prob = fminf(fmaxf(prob, 1.0e-4f), 1.0f - 1.0e-4f);
    bool pos = (target == 1.0f);
    float alpha_f = pos ? kAlpha : (1.0f - kAlpha);
    float pt = pos ? (1.0f - prob) : prob;
    float focal_w = alpha_f * pt * pt;
    float bce = fmaxf(pred, 0.0f) - pred * target + log1pf(expf(-fabsf(pred)));
    float loss = (mask == 0.0f) ? focal_w * bce : 0.0f;
    if (pos && prob < 0.8f) loss *= 4.0f;
    return loss;
}

// Relaxed device-scope accessors (R11/R12-proven: coherent-point traffic,
// no cache maintenance). Used ONLY for partials/losses/counters.
__device__ __forceinline__ void cstoref(float* p, float v) {
    __hip_atomic_store(p, v, __ATOMIC_RELAXED, __HIP_MEMORY_SCOPE_AGENT);
}
__device__ __forceinline__ float cloadf(const float* p) {
    return __hip_atomic_load(p, __ATOMIC_RELAXED, __HIP_MEMORY_SCOPE_AGENT);
}

// K1: gather only. target/pred/mask issued IN PARALLEL (no branch-dependent
// second round-trip). Normal coalesced stores to gvals (K1->K2 boundary
// publishes them). Block 0 resets the 9 counters.
__global__ void __launch_bounds__(kTpb1) gather_kernel(
        const float* __restrict__ pred, const float* __restrict__ target,
        const float* __restrict__ mask, const int* __restrict__ neg_idx,
        unsigned* __restrict__ ws) {
    if (blockIdx.x == 0 && threadIdx.x < 9) ws[oCnt + threadIdx.x] = 0u;
    const int t = blockIdx.x * kTpb1 + threadIdx.x;
    if (t >= kB * kNumNeg) return;
    const int b = t / kNumNeg;
    const int j = t - b * kNumNeg;
    const size_t base = (size_t)b * kN;
    const int gi = neg_idx[(size_t)b * kNumNeg + j];
    const float tg = target[base + gi];      // three independent loads,
    const float pr = pred[base + gi];        // issued back-to-back: one
    const float mk = mask[base + gi];        // memory round-trip, not two
    unsigned outv;
    if (tg == 1.0f) {
        outv = kSentinel;
    } else {
        float v = loss_at(pr, tg, mk);
        outv = __float_as_uint(v);           // v >= 0, finite
    }
    ws[oGvals + (size_t)b * kNumNeg + j] = outv;
}

// K2: 512 stream blocks x 1024 threads (R11's proven stream shape). Per
// batch, the 64th arriver (relaxed fetch_add after vmcnt drain — R11-proven
// cheap at this count) runs the R10-proven 1024-thread radix select inline.
__global__ void __launch_bounds__(kTpb2) stream_select_kernel(
        const float* __restrict__ pred, const float* __restrict__ target,
        const float* __restrict__ mask, unsigned* __restrict__ ws,
        float* __restrict__ out) {
    const int blk = blockIdx.x;
    const int tid = threadIdx.x;
    const int wave = tid >> 6, lane = tid & 63;
    float* wsf = (float*)ws;

    __shared__ unsigned whist[2][kWaves][256];   // 32 KB ping-pong
    __shared__ float r0[kWaves], r1[kWaves], r2[kWaves], r3[kWaves];
    __shared__ float red[kWaves];
    __shared__ float sh_np, sh_ps;
    __shared__ unsigned sh_krem, sh_prefix;
    __shared__ int sh_done, sh_last;

    // ---- stream role ----
    const int b = blk >> 6;
    const int slice = blk & 63;
    const size_t base = (size_t)b * kN;
    const float4* t4 = (const float4*)(target + base);
    const int tb = slice * kTpb2 + tid;          // [0, 65536)
    constexpr int kStride = kStreamPerB * kTpb2; // 65536; nvec = 4*kStride
    float4 v0 = t4[tb];
    float4 v1 = t4[tb + kStride];
    float4 v2 = t4[tb + 2 * kStride];
    float4 v3 = t4[tb + 3 * kStride];

    float cnt = 0.0f, psum = 0.0f;
    const float4 vv[4] = {v0, v1, v2, v3};
    #pragma unroll
    for (int it = 0; it < 4; ++it) {
        const int i = tb + it * kStride;
        float tvv[4] = {vv[it].x, vv[it].y, vv[it].z, vv[it].w};
        #pragma unroll
        for (int c = 0; c < 4; ++c) {
            if (tvv[c] == 1.0f) {
                int gi = i * 4 + c;
                cnt += 1.0f;
                psum += loss_at(pred[base + gi], 1.0f, mask[base + gi]);
            }
        }
    }
    #pragma unroll
    for (int off = 32; off > 0; off >>= 1) {
        cnt  += __shfl_down(cnt, off);
        psum += __shfl_down(psum, off);
    }
    if (lane == 0) { r0[wave] = cnt; r1[wave] = psum; }
    __syncthreads();
    if (tid == 0) {
        float c = 0.0f, p = 0.0f;
        for (int w = 0; w < kWaves; ++w) { c += r0[w]; p += r1[w]; }
        float* slot = wsf + oPartials + ((size_t)b * kStreamPerB + slice) * 2;
        cstoref(&slot[0], c);
        cstoref(&slot[1], p);
        asm volatile("s_waitcnt vmcnt(0)" ::: "memory");   // stores at CP
        unsigned old = __hip_atomic_fetch_add(&ws[oCnt + b], 1u,
                                              __ATOMIC_RELAXED,
                                              __HIP_MEMORY_SCOPE_AGENT);
        sh_last = (old == (unsigned)(kStreamPerB - 1));
    }
    __syncthreads();
    if (!sh_last) return;

    // ============ finisher: 1024-thread radix select for batch b ============
    for (int i = tid; i < 2 * kWaves * 256; i += kTpb2)
        ((unsigned*)whist)[i] = 0u;
    __syncthreads();

    // gvals: NORMAL cached loads (K1->K2 boundary; R12-proven correct)
    unsigned vreg[kVPer];
    float mcnt = 0.0f, msum = 0.0f;
    #pragma unroll
    for (int it = 0; it < kVPer; ++it) {
        const int j = tid + it * kTpb2;
        unsigned v = kSentinel;
        if (j < kNumNeg) v = ws[oGvals + (size_t)b * kNumNeg + j];
        vreg[it] = v;
        if (v != kSentinel) {
            mcnt += 1.0f;
            msum += __uint_as_float(v);
            atomicAdd(&whist[0][wave][v >> 24], 1u);   // v>=0 → bucket <128
        }
    }
    float c = 0.0f, p = 0.0f;
    if (tid < kStreamPerB) {   // partials: relaxed loads
        const float* slot = wsf + oPartials + ((size_t)b * kStreamPerB + tid) * 2;
        c = cloadf(&slot[0]); p = cloadf(&slot[1]);
    }
    #pragma unroll
    for (int off = 32; off > 0; off >>= 1) {
        mcnt += __shfl_down(mcnt, off);
        msum += __shfl_down(msum, off);
        c    += __shfl_down(c, off);
        p    += __shfl_down(p, off);
    }
    if (lane == 0) { r0[wave] = mcnt; r1[wave] = msum; r2[wave] = c; r3[wave] = p; }
    __syncthreads();
    float my_loss = 0.0f;              // only thread 0's value used
    if (tid == 0) {
        float a0 = 0, a1 = 0, a2 = 0, a3 = 0;
        for (int w = 0; w < kWaves; ++w) { a0 += r0[w]; a1 += r1[w]; a2 += r2[w]; a3 += r3[w]; }
        sh_np = a2; sh_ps = a3;
        const int num_pos = (int)a2;
        const int m = (int)a0;
        const int k = (num_pos > 0) ? min(kRatio * num_pos, kNumNeg) : kNumHard;
        if (k >= m) {
            my_loss = (a3 + a1) / fmaxf(a2, 1.0f);
            sh_done = 1;
        } else {
            sh_done = 0;
            sh_krem = (unsigned)k;
            sh_prefix = 0u;
        }
    }
    __syncthreads();

    if (!sh_done) {
        #pragma unroll
        for (int pass = 0; pass < 4; ++pass) {
            const int shift = 24 - 8 * pass;
            if (pass > 0) {
                const unsigned pmask = 0xFFFFFFFFu << (shift + 8);
                const unsigned pval = sh_prefix;
                #pragma unroll
                for (int it = 0; it < kVPer; ++it) {
                    unsigned v = vreg[it];
                    if (v != kSentinel && (v & pmask) == pval)
                        atomicAdd(&whist[pass & 1][wave][(v >> shift) & 255u], 1u);
                }
                __syncthreads();
            }
            if (wave == 0) {
                const int binbase = 252 - 4 * lane;
                unsigned h0 = 0, h1 = 0, h2 = 0, h3 = 0;
                #pragma unroll
                for (int w = 0; w < kWaves; ++w) {
                    uint4 q = *(const uint4*)&whist[pass & 1][w][binbase];
                    h0 += q.x; h1 += q.y; h2 += q.z; h3 += q.w;
                }
                const unsigned d0 = h3, d1 = h2, d2 = h1, d3 = h0;
                const unsigned p0 = d0, p1 = p0 + d1, p2 = p1 + d2, p3 = p2 + d3;
                unsigned acc = p3;
                #pragma unroll
                for (int off = 1; off < 64; off <<= 1) {
                    unsigned y = __shfl_up(acc, off);
                    if (lane >= off) acc += y;
                }
                const unsigned excl = acc - p3;        // sfx of bin binbase+4
                const unsigned krem = sh_krem;
                const unsigned s0 = excl + p0, s1 = excl + p1,
                               s2 = excl + p2, s3 = excl + p3;
                if (s0 >= krem && excl < krem) {
                    sh_krem = krem - (s0 - d0);
                    sh_prefix |= (unsigned)(binbase + 3) << shift;
                } else if (s1 >= krem && s0 < krem) {
                    sh_krem = krem - (s1 - d1);
                    sh_prefix |= (unsigned)(binbase + 2) << shift;
                } else if (s2 >= krem && s1 < krem) {
                    sh_krem = krem - (s2 - d2);
                    sh_prefix |= (unsigned)(binbase + 1) << shift;
                } else if (s3 >= krem && s2 < krem) {
                    sh_krem = krem - (s3 - d3);
                    sh_prefix |= (unsigned)(binbase + 0) << shift;
                }
            } else {
                // waves 1-15: zero the OTHER buffer for the next pass
                for (int i = tid - 64; i < kWaves * 256; i += kTpb2 - 64)
                    ((unsigned*)whist[(pass + 1) & 1])[i] = 0u;
            }
            __syncthreads();
        }

        const unsigned tbits = sh_prefix;
        float gsum = 0.0f;
        #pragma unroll
        for (int it = 0; it < kVPer; ++it) {
            unsigned v = vreg[it];
            if (v != kSentinel && v > tbits) gsum += __uint_as_float(v);
        }
        #pragma unroll
        for (int off = 32; off > 0; off >>= 1) gsum += __shfl_down(gsum, off);
        if (lane == 0) red[wave] = gsum;
        __syncthreads();
        if (tid == 0) {
            float sum_gt = 0.0f;
            for (int w = 0; w < kWaves; ++w) sum_gt += red[w];
            const float tval = __uint_as_float(tbits);
            const float neg_sum = sum_gt + (float)sh_krem * tval;
            my_loss = (sh_ps + neg_sum) / fmaxf(sh_np, 1.0f);
        }
    }

    // ---- finalize: 8th batch-finisher computes the mean (fixed order) ----
    if (tid == 0) {
        cstoref(&wsf[oBatchLoss + b], my_loss);
        asm volatile("s_waitcnt vmcnt(0)" ::: "memory");
        unsigned old = __hip_atomic_fetch_add(&ws[oGCnt], 1u, __ATOMIC_RELAXED,
                                              __HIP_MEMORY_SCOPE_AGENT);
        if (old == (unsigned)(kB - 1)) {
            float s = 0.0f;
            for (int i = 0; i < kB; ++i)
                s += cloadf(&wsf[oBatchLoss + i]);
            out[0] = s / (float)kB;
        }
    }
}

} // namespace

extern "C" void kernel_launch(void* const* d_in, const int* in_sizes, int n_in,
                              void* d_out, int out_size, void* d_ws, size_t ws_size,
                              hipStream_t stream) {
    const float* pred   = (const float*)d_in[0];
    const float* target = (const float*)d_in[1];
    const float* mask   = (const float*)d_in[2];
    const int*   negidx = (const int*)d_in[3];
    unsigned* ws = (unsigned*)d_ws;
    float* out = (float*)d_out;

    gather_kernel<<<dim3(kGatherBlocks), dim3(kTpb1), 0, stream>>>(
        pred, target, mask, negidx, ws);
    stream_select_kernel<<<dim3(kStreamBlocks), dim3(kTpb2), 0, stream>>>(
        pred, target, mask, ws, out);
}

// Round 14
// 27.493 us; speedup vs baseline: 2.1387x; 1.2201x over previous
//
#include <hip/hip_runtime.h>
#include <math.h>

namespace {

constexpr float kAlpha   = 0.75f;
constexpr int   kNumNeg  = 10000;
constexpr int   kNumHard = 100;
constexpr int   kRatio   = 100;
constexpr int   kB       = 8;
constexpr int   kN       = 64 * 128 * 128;   // 1048576
constexpr int   kTpb1    = 256;
constexpr int   kSlices  = 256;                       // stream blocks per batch
constexpr int   kGatherBlocksReal = (kB * kNumNeg + kTpb1 - 1) / kTpb1;  // 313
constexpr int   kGrid1   = 2560;                      // 2048 stream + 512 gather slots
constexpr int   kTpbSel  = 1024;
constexpr int   kWavesSel = kTpbSel / 64;             // 16
constexpr int   kVPerThread = (kNumNeg + kTpbSel - 1) / kTpbSel;  // 10
constexpr unsigned kSentinel = 0xFFFFFFFFu;

typedef float f32x4 __attribute__((ext_vector_type(4)));

__device__ __forceinline__ float loss_at(float pred, float target, float mask) {
    float prob = 1.0f / (1.0f + expf(-pred));
    prob = fminf(fmaxf(prob, 1.0e-4f), 1.0f - 1.0e-4f);
    bool pos = (target == 1.0f);
    float alpha_f = pos ? kAlpha : (1.0f - kAlpha);
    float pt = pos ? (1.0f - prob) : prob;
    float focal_w = alpha_f * pt * pt;
    float bce = fmaxf(pred, 0.0f) - pred * target + log1pf(expf(-fabsf(pred)));
    float loss = (mask == 0.0f) ? focal_w * bce : 0.0f;
    if (pos && prob < 0.8f) loss *= 4.0f;
    return loss;
}

// Stage 1 (R10 structure, final): gather slots interleaved every 5th block;
// stream loads are NON-TEMPORAL (read-once → keep L2/L3 for gather lines);
// gather issues target/pred/mask independently (one round-trip, not two).
__global__ void __launch_bounds__(kTpb1) stage1_kernel(
        const float* __restrict__ pred, const float* __restrict__ target,
        const float* __restrict__ mask, const int* __restrict__ neg_idx,
        float* __restrict__ partials, unsigned* __restrict__ gvals,
        unsigned* __restrict__ counter) {
    const int blk = blockIdx.x;
    if (blk == 0 && threadIdx.x == 0) *counter = 0u;

    if (blk % 5 == 2) {
        // ---- gather slot ----
        const int g = blk / 5;                        // 0..511; real: <313
        if (g >= kGatherBlocksReal) return;
        const int t = g * kTpb1 + threadIdx.x;
        if (t < kB * kNumNeg) {
            const int b = t / kNumNeg;
            const int j = t - b * kNumNeg;
            const size_t base = (size_t)b * kN;
            const int gi = neg_idx[(size_t)b * kNumNeg + j];
            const float tg = target[base + gi];       // three independent
            const float pr = pred[base + gi];         // loads, issued
            const float mk = mask[base + gi];         // back-to-back
            unsigned outv;
            if (tg == 1.0f) {
                outv = kSentinel;
            } else {
                float v = loss_at(pr, tg, mk);
                outv = __float_as_uint(v);            // v >= 0, finite
            }
            gvals[(size_t)b * kNumNeg + j] = outv;
        }
        return;
    }

    // ---- stream slot: sid covers 0..2047 exactly once ----
    const int sid = blk - (blk + 2) / 5;
    const int b = sid >> 8;                           // 256 slices per batch
    const int slice = sid & 255;
    const size_t base = (size_t)b * kN;
    const f32x4* t4 = (const f32x4*)(target + base);
    const int tb = slice * kTpb1 + threadIdx.x;       // [0, 65536)
    constexpr int kStride = kSlices * kTpb1;          // 65536; nvec = 4*kStride
    f32x4 v0 = __builtin_nontemporal_load(t4 + tb);
    f32x4 v1 = __builtin_nontemporal_load(t4 + tb + kStride);
    f32x4 v2 = __builtin_nontemporal_load(t4 + tb + 2 * kStride);
    f32x4 v3 = __builtin_nontemporal_load(t4 + tb + 3 * kStride);

    float cnt = 0.0f, psum = 0.0f;
    const f32x4 vv[4] = {v0, v1, v2, v3};
    #pragma unroll
    for (int it = 0; it < 4; ++it) {
        const int i = tb + it * kStride;
        #pragma unroll
        for (int c = 0; c < 4; ++c) {
            if (vv[it][c] == 1.0f) {
                int gi = i * 4 + c;
                cnt += 1.0f;
                psum += loss_at(pred[base + gi], 1.0f, mask[base + gi]);
            }
        }
    }
    #pragma unroll
    for (int off = 32; off > 0; off >>= 1) {
        cnt  += __shfl_down(cnt, off);
        psum += __shfl_down(psum, off);
    }
    __shared__ float sc[kTpb1 / 64], sp[kTpb1 / 64];
    const int wave = threadIdx.x / 64, lane = threadIdx.x % 64;
    if (lane == 0) { sc[wave] = cnt; sp[wave] = psum; }
    __syncthreads();
    if (threadIdx.x == 0) {
        float c = 0.0f, p = 0.0f;
        for (int w = 0; w < kTpb1 / 64; ++w) { c += sc[w]; p += sp[w]; }
        float* slot = partials + ((size_t)b * kSlices + slice) * 2;
        slot[0] = c; slot[1] = p;
    }
}

// Stage 2: unchanged from round 9/10 (proven). One block per batch; 4-pass
// radix select, ping-pong histograms, wave-0 in-register suffix scan; TRUE
// last arriver (counter reset by stage1) computes the final mean.
__global__ void __launch_bounds__(kTpbSel) select_kernel(
        const unsigned* __restrict__ gvals, const float* __restrict__ partials,
        float* __restrict__ batch_loss, unsigned* __restrict__ counter,
        float* __restrict__ out) {
    __shared__ unsigned whist[2][kWavesSel][256];     // 32 KB ping-pong
    __shared__ float r0[kWavesSel], r1[kWavesSel], r2[kWavesSel], r3[kWavesSel];
    __shared__ float red[kWavesSel];
    __shared__ float sh_np, sh_ps;
    __shared__ unsigned sh_krem, sh_prefix;
    __shared__ int sh_done;

    const int b = blockIdx.x;
    const int tid = threadIdx.x;
    const int wave = tid >> 6, lane = tid & 63;

    for (int i = tid; i < 2 * kWavesSel * 256; i += kTpbSel)
        ((unsigned*)whist)[i] = 0u;
    __syncthreads();

    unsigned vreg[kVPerThread];
    float mcnt = 0.0f, msum = 0.0f;
    #pragma unroll
    for (int it = 0; it < kVPerThread; ++it) {
        const int j = tid + it * kTpbSel;
        unsigned v = kSentinel;
        if (j < kNumNeg) v = gvals[(size_t)b * kNumNeg + j];
        vreg[it] = v;
        if (v != kSentinel) {
            mcnt += 1.0f;
            msum += __uint_as_float(v);
            atomicAdd(&whist[0][wave][v >> 24], 1u);  // v>=0 → bucket <128
        }
    }
    float c = 0.0f, p = 0.0f;
    if (tid < kSlices) {
        const float* slot = partials + ((size_t)b * kSlices + tid) * 2;
        c = slot[0]; p = slot[1];
    }
    #pragma unroll
    for (int off = 32; off > 0; off >>= 1) {
        mcnt += __shfl_down(mcnt, off);
        msum += __shfl_down(msum, off);
        c    += __shfl_down(c, off);
        p    += __shfl_down(p, off);
    }
    if (lane == 0) { r0[wave] = mcnt; r1[wave] = msum; r2[wave] = c; r3[wave] = p; }
    __syncthreads();
    float my_loss = 0.0f;              // only thread 0's value is used
    if (tid == 0) {
        float a0 = 0, a1 = 0, a2 = 0, a3 = 0;
        for (int w = 0; w < kWavesSel; ++w) { a0 += r0[w]; a1 += r1[w]; a2 += r2[w]; a3 += r3[w]; }
        sh_np = a2; sh_ps = a3;
        const int num_pos = (int)a2;
        const int m = (int)a0;
        const int k = (num_pos > 0) ? min(kRatio * num_pos, kNumNeg) : kNumHard;
        if (k >= m) {
            my_loss = (a3 + a1) / fmaxf(a2, 1.0f);
            sh_done = 1;
        } else {
            sh_done = 0;
            sh_krem = (unsigned)k;
            sh_prefix = 0u;
        }
    }
    __syncthreads();

    if (!sh_done) {
        #pragma unroll
        for (int pass = 0; pass < 4; ++pass) {
            const int shift = 24 - 8 * pass;
            if (pass > 0) {
                const unsigned pmask = 0xFFFFFFFFu << (shift + 8);
                const unsigned pval = sh_prefix;
                #pragma unroll
                for (int it = 0; it < kVPerThread; ++it) {
                    unsigned v = vreg[it];
                    if (v != kSentinel && (v & pmask) == pval)
                        atomicAdd(&whist[pass & 1][wave][(v >> shift) & 255u], 1u);
                }
                __syncthreads();
            }
            if (wave == 0) {
                const int binbase = 252 - 4 * lane;
                unsigned h0 = 0, h1 = 0, h2 = 0, h3 = 0;
                #pragma unroll
                for (int w = 0; w < kWavesSel; ++w) {
                    uint4 q = *(const uint4*)&whist[pass & 1][w][binbase];
                    h0 += q.x; h1 += q.y; h2 += q.z; h3 += q.w;
                }
                const unsigned d0 = h3, d1 = h2, d2 = h1, d3 = h0;
                const unsigned p0 = d0, p1 = p0 + d1, p2 = p1 + d2, p3 = p2 + d3;
                unsigned acc = p3;
                #pragma unroll
                for (int off = 1; off < 64; off <<= 1) {
                    unsigned y = __shfl_up(acc, off);
                    if (lane >= off) acc += y;
                }
                const unsigned excl = acc - p3;       // sfx of bin binbase+4
                const unsigned krem = sh_krem;
                const unsigned s0 = excl + p0, s1 = excl + p1,
                               s2 = excl + p2, s3 = excl + p3;
                if (s0 >= krem && excl < krem) {
                    sh_krem = krem - (s0 - d0);
                    sh_prefix |= (unsigned)(binbase + 3) << shift;
                } else if (s1 >= krem && s0 < krem) {
                    sh_krem = krem - (s1 - d1);
                    sh_prefix |= (unsigned)(binbase + 2) << shift;
                } else if (s2 >= krem && s1 < krem) {
                    sh_krem = krem - (s2 - d2);
                    sh_prefix |= (unsigned)(binbase + 1) << shift;
                } else if (s3 >= krem && s2 < krem) {
                    sh_krem = krem - (s3 - d3);
                    sh_prefix |= (unsigned)(binbase + 0) << shift;
                }
            } else {
                for (int i = tid - 64; i < kWavesSel * 256; i += kTpbSel - 64)
                    ((unsigned*)whist[(pass + 1) & 1])[i] = 0u;
            }
            __syncthreads();
        }

        const unsigned tbits = sh_prefix;
        float gsum = 0.0f;
        #pragma unroll
        for (int it = 0; it < kVPerThread; ++it) {
            unsigned v = vreg[it];
            if (v != kSentinel && v > tbits) gsum += __uint_as_float(v);
        }
        #pragma unroll
        for (int off = 32; off > 0; off >>= 1) gsum += __shfl_down(gsum, off);
        if (lane == 0) red[wave] = gsum;
        __syncthreads();
        if (tid == 0) {
            float sum_gt = 0.0f;
            for (int w = 0; w < kWavesSel; ++w) sum_gt += red[w];
            const float tval = __uint_as_float(tbits);
            const float neg_sum = sum_gt + (float)sh_krem * tval;
            my_loss = (sh_ps + neg_sum) / fmaxf(sh_np, 1.0f);
        }
    }

    if (tid == 0) {
        __hip_atomic_store(&batch_loss[b], my_loss, __ATOMIC_RELEASE,
                           __HIP_MEMORY_SCOPE_AGENT);
        unsigned old = __hip_atomic_fetch_add(counter, 1u, __ATOMIC_ACQ_REL,
                                              __HIP_MEMORY_SCOPE_AGENT);
        if (old == (unsigned)(kB - 1)) {
            float s = 0.0f;
            for (int i = 0; i < kB; ++i)
                s += __hip_atomic_load(&batch_loss[i], __ATOMIC_ACQUIRE,
                                       __HIP_MEMORY_SCOPE_AGENT);
            out[0] = s / (float)kB;
        }
    }
}

} // namespace

extern "C" void kernel_launch(void* const* d_in, const int* in_sizes, int n_in,
                              void* d_out, int out_size, void* d_ws, size_t ws_size,
                              hipStream_t stream) {
    const float* pred   = (const float*)d_in[0];
    const float* target = (const float*)d_in[1];
    const float* mask   = (const float*)d_in[2];
    const int*   negidx = (const int*)d_in[3];
    float* ws = (float*)d_ws;
    float*    partials   = ws;                         // 2048*2 floats
    float*    batch_loss = ws + 4096;                  // 8 floats
    unsigned* counter    = (unsigned*)(ws + 4104);     // 1 uint
    unsigned* gvals      = (unsigned*)(ws + 4112);     // 80000 uints
    float* out = (float*)d_out;

    stage1_kernel<<<dim3(kGrid1), dim3(kTpb1), 0, stream>>>(
        pred, target, mask, negidx, partials, gvals, counter);
    select_kernel<<<dim3(kB), dim3(kTpbSel), 0, stream>>>(
        gvals, partials, batch_loss, counter, out);
}

// Round 15
// 26.390 us; speedup vs baseline: 2.2281x; 1.0418x over previous
//
#include <hip/hip_runtime.h>
#include <math.h>

namespace {

constexpr float kAlpha   = 0.75f;
constexpr int   kNumNeg  = 10000;
constexpr int   kNumHard = 100;
constexpr int   kRatio   = 100;
constexpr int   kB       = 8;
constexpr int   kN       = 64 * 128 * 128;   // 1048576
constexpr int   kTpb1    = 256;
constexpr int   kSlices  = 256;                       // stream blocks per batch
constexpr int   kGatherBlocksReal = (kB * kNumNeg + kTpb1 - 1) / kTpb1;  // 313
constexpr int   kGrid1   = 2560;                      // 2048 stream + 512 gather slots
constexpr int   kTpbSel  = 1024;
constexpr int   kWavesSel = kTpbSel / 64;             // 16
constexpr int   kU4PerBatch = kNumNeg / 4;            // 2500 uint4s
constexpr int   kVPerThread = 12;                     // 3 uint4 per thread
constexpr unsigned kSentinel = 0xFFFFFFFFu;

typedef float f32x4 __attribute__((ext_vector_type(4)));

__device__ __forceinline__ float loss_at(float pred, float target, float mask) {
    float prob = 1.0f / (1.0f + expf(-pred));
    prob = fminf(fmaxf(prob, 1.0e-4f), 1.0f - 1.0e-4f);
    bool pos = (target == 1.0f);
    float alpha_f = pos ? kAlpha : (1.0f - kAlpha);
    float pt = pos ? (1.0f - prob) : prob;
    float focal_w = alpha_f * pt * pt;
    float bce = fmaxf(pred, 0.0f) - pred * target + log1pf(expf(-fabsf(pred)));
    float loss = (mask == 0.0f) ? focal_w * bce : 0.0f;
    if (pos && prob < 0.8f) loss *= 4.0f;
    return loss;
}

// Stage 1 (R14, unchanged — proven 27.5 µs best): gather slots interleaved
// every 5th block; non-temporal stream loads; gather's 3 loads independent.
__global__ void __launch_bounds__(kTpb1) stage1_kernel(
        const float* __restrict__ pred, const float* __restrict__ target,
        const float* __restrict__ mask, const int* __restrict__ neg_idx,
        float* __restrict__ partials, unsigned* __restrict__ gvals,
        unsigned* __restrict__ counter) {
    const int blk = blockIdx.x;
    if (blk == 0 && threadIdx.x == 0) *counter = 0u;

    if (blk % 5 == 2) {
        // ---- gather slot ----
        const int g = blk / 5;                        // 0..511; real: <313
        if (g >= kGatherBlocksReal) return;
        const int t = g * kTpb1 + threadIdx.x;
        if (t < kB * kNumNeg) {
            const int b = t / kNumNeg;
            const int j = t - b * kNumNeg;
            const size_t base = (size_t)b * kN;
            const int gi = __builtin_nontemporal_load(neg_idx + (size_t)b * kNumNeg + j);
            const float tg = target[base + gi];       // three independent
            const float pr = pred[base + gi];         // loads, issued
            const float mk = mask[base + gi];         // back-to-back
            unsigned outv;
            if (tg == 1.0f) {
                outv = kSentinel;
            } else {
                float v = loss_at(pr, tg, mk);
                outv = __float_as_uint(v);            // v >= 0, finite
            }
            gvals[(size_t)b * kNumNeg + j] = outv;
        }
        return;
    }

    // ---- stream slot: sid covers 0..2047 exactly once ----
    const int sid = blk - (blk + 2) / 5;
    const int b = sid >> 8;                           // 256 slices per batch
    const int slice = sid & 255;
    const size_t base = (size_t)b * kN;
    const f32x4* t4 = (const f32x4*)(target + base);
    const int tb = slice * kTpb1 + threadIdx.x;       // [0, 65536)
    constexpr int kStride = kSlices * kTpb1;          // 65536; nvec = 4*kStride
    f32x4 v0 = __builtin_nontemporal_load(t4 + tb);
    f32x4 v1 = __builtin_nontemporal_load(t4 + tb + kStride);
    f32x4 v2 = __builtin_nontemporal_load(t4 + tb + 2 * kStride);
    f32x4 v3 = __builtin_nontemporal_load(t4 + tb + 3 * kStride);

    float cnt = 0.0f, psum = 0.0f;
    const f32x4 vv[4] = {v0, v1, v2, v3};
    #pragma unroll
    for (int it = 0; it < 4; ++it) {
        const int i = tb + it * kStride;
        #pragma unroll
        for (int c = 0; c < 4; ++c) {
            if (vv[it][c] == 1.0f) {
                int gi = i * 4 + c;
                cnt += 1.0f;
                psum += loss_at(pred[base + gi], 1.0f, mask[base + gi]);
            }
        }
    }
    #pragma unroll
    for (int off = 32; off > 0; off >>= 1) {
        cnt  += __shfl_down(cnt, off);
        psum += __shfl_down(psum, off);
    }
    __shared__ float sc[kTpb1 / 64], sp[kTpb1 / 64];
    const int wave = threadIdx.x / 64, lane = threadIdx.x % 64;
    if (lane == 0) { sc[wave] = cnt; sp[wave] = psum; }
    __syncthreads();
    if (threadIdx.x == 0) {
        float c = 0.0f, p = 0.0f;
        for (int w = 0; w < kTpb1 / 64; ++w) { c += sc[w]; p += sp[w]; }
        float* slot = partials + ((size_t)b * kSlices + slice) * 2;
        slot[0] = c; slot[1] = p;
    }
}

// Stage 2: R14 select + two load-path tweaks: gvals read as 3x uint4/thread
// (1KB/wave/instruction) and HOISTED above the whist zeroing so the L2/L3
// latency hides under the LDS-clear instead of serializing after it.
__global__ void __launch_bounds__(kTpbSel) select_kernel(
        const unsigned* __restrict__ gvals, const float* __restrict__ partials,
        float* __restrict__ batch_loss, unsigned* __restrict__ counter,
        float* __restrict__ out) {
    __shared__ unsigned whist[2][kWavesSel][256];     // 32 KB ping-pong
    __shared__ float r0[kWavesSel], r1[kWavesSel], r2[kWavesSel], r3[kWavesSel];
    __shared__ float red[kWavesSel];
    __shared__ float sh_np, sh_ps;
    __shared__ unsigned sh_krem, sh_prefix;
    __shared__ int sh_done;

    const int b = blockIdx.x;
    const int tid = threadIdx.x;
    const int wave = tid >> 6, lane = tid & 63;

    // ---- hoisted gvals loads (independent of LDS; issue before zeroing) ----
    const uint4* g4 = (const uint4*)(gvals + (size_t)b * kNumNeg);
    uint4 q0 = g4[tid];                                // idx < 1024 < 2500
    uint4 q1 = g4[tid + 1024];                         // idx < 2048 < 2500
    uint4 q2 = (tid < kU4PerBatch - 2048)              // idx < 2500
                   ? g4[tid + 2048]
                   : make_uint4(kSentinel, kSentinel, kSentinel, kSentinel);

    // partials (also independent of LDS)
    float c = 0.0f, p = 0.0f;
    if (tid < kSlices) {
        const float* slot = partials + ((size_t)b * kSlices + tid) * 2;
        c = slot[0]; p = slot[1];
    }

    for (int i = tid; i < 2 * kWavesSel * 256; i += kTpbSel)
        ((unsigned*)whist)[i] = 0u;
    __syncthreads();

    // unpack; count/sum valid; pass-0 histogram
    unsigned vreg[kVPerThread] = {q0.x, q0.y, q0.z, q0.w,
                                  q1.x, q1.y, q1.z, q1.w,
                                  q2.x, q2.y, q2.z, q2.w};
    float mcnt = 0.0f, msum = 0.0f;
    #pragma unroll
    for (int it = 0; it < kVPerThread; ++it) {
        unsigned v = vreg[it];
        if (v != kSentinel) {
            mcnt += 1.0f;
            msum += __uint_as_float(v);
            atomicAdd(&whist[0][wave][v >> 24], 1u);  // v>=0 → bucket <128
        }
    }
    #pragma unroll
    for (int off = 32; off > 0; off >>= 1) {
        mcnt += __shfl_down(mcnt, off);
        msum += __shfl_down(msum, off);
        c    += __shfl_down(c, off);
        p    += __shfl_down(p, off);
    }
    if (lane == 0) { r0[wave] = mcnt; r1[wave] = msum; r2[wave] = c; r3[wave] = p; }
    __syncthreads();
    float my_loss = 0.0f;              // only thread 0's value is used
    if (tid == 0) {
        float a0 = 0, a1 = 0, a2 = 0, a3 = 0;
        for (int w = 0; w < kWavesSel; ++w) { a0 += r0[w]; a1 += r1[w]; a2 += r2[w]; a3 += r3[w]; }
        sh_np = a2; sh_ps = a3;
        const int num_pos = (int)a2;
        const int m = (int)a0;
        const int k = (num_pos > 0) ? min(kRatio * num_pos, kNumNeg) : kNumHard;
        if (k >= m) {
            my_loss = (a3 + a1) / fmaxf(a2, 1.0f);
            sh_done = 1;
        } else {
            sh_done = 0;
            sh_krem = (unsigned)k;
            sh_prefix = 0u;
        }
    }
    __syncthreads();

    if (!sh_done) {
        #pragma unroll
        for (int pass = 0; pass < 4; ++pass) {
            const int shift = 24 - 8 * pass;
            if (pass > 0) {
                const unsigned pmask = 0xFFFFFFFFu << (shift + 8);
                const unsigned pval = sh_prefix;
                #pragma unroll
                for (int it = 0; it < kVPerThread; ++it) {
                    unsigned v = vreg[it];
                    if (v != kSentinel && (v & pmask) == pval)
                        atomicAdd(&whist[pass & 1][wave][(v >> shift) & 255u], 1u);
                }
                __syncthreads();
            }
            if (wave == 0) {
                const int binbase = 252 - 4 * lane;
                unsigned h0 = 0, h1 = 0, h2 = 0, h3 = 0;
                #pragma unroll
                for (int w = 0; w < kWavesSel; ++w) {
                    uint4 q = *(const uint4*)&whist[pass & 1][w][binbase];
                    h0 += q.x; h1 += q.y; h2 += q.z; h3 += q.w;
                }
                const unsigned d0 = h3, d1 = h2, d2 = h1, d3 = h0;
                const unsigned p0 = d0, p1 = p0 + d1, p2 = p1 + d2, p3 = p2 + d3;
                unsigned acc = p3;
                #pragma unroll
                for (int off = 1; off < 64; off <<= 1) {
                    unsigned y = __shfl_up(acc, off);
                    if (lane >= off) acc += y;
                }
                const unsigned excl = acc - p3;       // sfx of bin binbase+4
                const unsigned krem = sh_krem;
                const unsigned s0 = excl + p0, s1 = excl + p1,
                               s2 = excl + p2, s3 = excl + p3;
                if (s0 >= krem && excl < krem) {
                    sh_krem = krem - (s0 - d0);
                    sh_prefix |= (unsigned)(binbase + 3) << shift;
                } else if (s1 >= krem && s0 < krem) {
                    sh_krem = krem - (s1 - d1);
                    sh_prefix |= (unsigned)(binbase + 2) << shift;
                } else if (s2 >= krem && s1 < krem) {
                    sh_krem = krem - (s2 - d2);
                    sh_prefix |= (unsigned)(binbase + 1) << shift;
                } else if (s3 >= krem && s2 < krem) {
                    sh_krem = krem - (s3 - d3);
                    sh_prefix |= (unsigned)(binbase + 0) << shift;
                }
            } else {
                for (int i = tid - 64; i < kWavesSel * 256; i += kTpbSel - 64)
                    ((unsigned*)whist[(pass + 1) & 1])[i] = 0u;
            }
            __syncthreads();
        }

        const unsigned tbits = sh_prefix;
        float gsum = 0.0f;
        #pragma unroll
        for (int it = 0; it < kVPerThread; ++it) {
            unsigned v = vreg[it];
            if (v != kSentinel && v > tbits) gsum += __uint_as_float(v);
        }
        #pragma unroll
        for (int off = 32; off > 0; off >>= 1) gsum += __shfl_down(gsum, off);
        if (lane == 0) red[wave] = gsum;
        __syncthreads();
        if (tid == 0) {
            float sum_gt = 0.0f;
            for (int w = 0; w < kWavesSel; ++w) sum_gt += red[w];
            const float tval = __uint_as_float(tbits);
            const float neg_sum = sum_gt + (float)sh_krem * tval;
            my_loss = (sh_ps + neg_sum) / fmaxf(sh_np, 1.0f);
        }
    }

    if (tid == 0) {
        __hip_atomic_store(&batch_loss[b], my_loss, __ATOMIC_RELEASE,
                           __HIP_MEMORY_SCOPE_AGENT);
        unsigned old = __hip_atomic_fetch_add(counter, 1u, __ATOMIC_ACQ_REL,
                                              __HIP_MEMORY_SCOPE_AGENT);
        if (old == (unsigned)(kB - 1)) {
            float s = 0.0f;
            for (int i = 0; i < kB; ++i)
                s += __hip_atomic_load(&batch_loss[i], __ATOMIC_ACQUIRE,
                                       __HIP_MEMORY_SCOPE_AGENT);
            out[0] = s / (float)kB;
        }
    }
}

} // namespace

extern "C" void kernel_launch(void* const* d_in, const int* in_sizes, int n_in,
                              void* d_out, int out_size, void* d_ws, size_t ws_size,
                              hipStream_t stream) {
    const float* pred   = (const float*)d_in[0];
    const float* target = (const float*)d_in[1];
    const float* mask   = (const float*)d_in[2];
    const int*   negidx = (const int*)d_in[3];
    float* ws = (float*)d_ws;
    float*    partials   = ws;                         // 2048*2 floats
    float*    batch_loss = ws + 4096;                  // 8 floats
    unsigned* counter    = (unsigned*)(ws + 4104);     // 1 uint
    unsigned* gvals      = (unsigned*)(ws + 4112);     // 80000 uints (16B-aligned)
    float* out = (float*)d_out;

    stage1_kernel<<<dim3(kGrid1), dim3(kTpb1), 0, stream>>>(
        pred, target, mask, negidx, partials, gvals, counter);
    select_kernel<<<dim3(kB), dim3(kTpbSel), 0, stream>>>(
        gvals, partials, batch_loss, counter, out);
}